// Round 1
// baseline (1292.006 us; speedup 1.0000x reference)
//
#include <hip/hip_runtime.h>

#define U_NUM 100000
#define NE    1600000
#define SEQL  5

// ws layout (bytes), all 16B-aligned where needed
#define OFF_DEG      0UL         // int[100000]
#define OFF_CURSOR   400000UL    // int[100000]
#define OFF_ROWSTART 800000UL    // int[100001]
#define OFF_DINV     1200016UL   // float[100000]
#define OFF_BSUM     1600016UL   // int[128]
#define OFF_CSR      1600528UL   // int[1600000]
#define OFF_A        8000528UL   // float[6400000]
#define OFF_B        33600528UL  // float[6400000]  (end 59200528)

__global__ __launch_bounds__(256) void k_count(const int* __restrict__ edge, int* __restrict__ deg) {
    int e = blockIdx.x * 256 + threadIdx.x;
    atomicAdd(&deg[edge[NE + e]], 1);
}

__global__ __launch_bounds__(256) void k_dinv(const int* __restrict__ deg, float* __restrict__ dinv) {
    int i = blockIdx.x * 256 + threadIdx.x;
    if (i < U_NUM) dinv[i] = rsqrtf((float)(deg[i] + 1));
}

__global__ __launch_bounds__(1024) void k_scanA(const int* __restrict__ deg, int* __restrict__ bsum) {
    __shared__ int sm[1024];
    int i = blockIdx.x * 1024 + threadIdx.x;
    sm[threadIdx.x] = (i < U_NUM) ? deg[i] : 0;
    __syncthreads();
    for (int off = 512; off > 0; off >>= 1) {
        if (threadIdx.x < off) sm[threadIdx.x] += sm[threadIdx.x + off];
        __syncthreads();
    }
    if (threadIdx.x == 0) bsum[blockIdx.x] = sm[0];
}

__global__ void k_scanB(int* bsum, int nb) {
    if (threadIdx.x == 0) {
        int acc = 0;
        for (int b = 0; b < nb; ++b) { int v = bsum[b]; bsum[b] = acc; acc += v; }
    }
}

__global__ __launch_bounds__(1024) void k_scanC(const int* __restrict__ deg, const int* __restrict__ bsum,
                                                int* __restrict__ row_start) {
    __shared__ int sm[1024];
    int t = threadIdx.x;
    int i = blockIdx.x * 1024 + t;
    int v = (i < U_NUM) ? deg[i] : 0;
    sm[t] = v;
    __syncthreads();
    for (int off = 1; off < 1024; off <<= 1) {
        int x = (t >= off) ? sm[t - off] : 0;
        __syncthreads();
        sm[t] += x;
        __syncthreads();
    }
    int incl = sm[t];
    int base = bsum[blockIdx.x];
    if (i < U_NUM) row_start[i] = base + incl - v;
    if (i == U_NUM - 1) row_start[U_NUM] = base + incl;
}

__global__ __launch_bounds__(256) void k_fill(const int* __restrict__ edge, const int* __restrict__ row_start,
                                              int* __restrict__ cursor, int* __restrict__ csr) {
    int e = blockIdx.x * 256 + threadIdx.x;
    int dst = edge[NE + e];
    int pos = row_start[dst] + atomicAdd(&cursor[dst], 1);
    csr[pos] = edge[e];
}

// out[r][d] = sum_k relu?(x[r][k]) * W[k][d]
__global__ __launch_bounds__(256) void k_gemm64(const float* __restrict__ x, const float* __restrict__ w,
                                                float* __restrict__ out, int relu_in) {
    __shared__ float wl[64 * 64];
    for (int i = threadIdx.x; i < 4096; i += 256) wl[i] = w[i];
    __syncthreads();
    int wid = threadIdx.x >> 6, lane = threadIdx.x & 63;
    for (int r = blockIdx.x * 4 + wid; r < U_NUM; r += gridDim.x * 4) {
        float xr = x[r * 64 + lane];
        if (relu_in) xr = fmaxf(xr, 0.f);
        float acc = 0.f;
#pragma unroll
        for (int k = 0; k < 64; ++k)
            acc = fmaf(__shfl(xr, k), wl[k * 64 + lane], acc);
        out[r * 64 + lane] = acc;
    }
}

// B = A * dinv^2 (self loop) + bias, vectorized float4 (idx over 1.6M float4s)
__global__ __launch_bounds__(256) void k_init(const float4* __restrict__ A4, const float* __restrict__ dinv,
                                              const float* __restrict__ bias, float4* __restrict__ B4) {
    int idx = blockIdx.x * 256 + threadIdx.x;
    float4 a = A4[idx];
    float di = dinv[idx >> 4];
    float s = di * di;
    const float4 b = ((const float4*)bias)[idx & 15];
    float4 o;
    o.x = fmaf(a.x, s, b.x);
    o.y = fmaf(a.y, s, b.y);
    o.z = fmaf(a.z, s, b.z);
    o.w = fmaf(a.w, s, b.w);
    B4[idx] = o;
}

// per dst node (one wave each): B[i] += sum_{e in csr row i} A[src_e] * dinv[i]*dinv[src_e]
__global__ __launch_bounds__(256) void k_gather(const float* __restrict__ xw, const float* __restrict__ dinv,
                                                const int* __restrict__ row_start, const int* __restrict__ csr,
                                                float* __restrict__ outb) {
    int i = blockIdx.x * 4 + (threadIdx.x >> 6);
    int lane = threadIdx.x & 63;
    int s0 = row_start[i], s1 = row_start[i + 1];
    float di = dinv[i];
    float acc = 0.f;
    for (int e = s0; e < s1; ++e) {
        int s = csr[e];
        acc = fmaf(xw[s * 64 + lane], di * dinv[s], acc);
    }
    outb[i * 64 + lane] += acc;
}

// per user (one wave each): attention -> gamma[5] -> uef[64]
__global__ __launch_bounds__(256) void k_attn(const int* __restrict__ edge_user, const float* __restrict__ ci_table,
                                              const float* __restrict__ at_w, const float* __restrict__ at_b,
                                              const float* __restrict__ d2_w, const float* __restrict__ d2_b,
                                              const float* __restrict__ ue, float* __restrict__ uef) {
    __shared__ float atw_t[64 * 65];  // [j][d], padded stride 65, rows j>=48 zero
    __shared__ float atb_l[64];
    __shared__ float d2w_l[80];
    for (int i = threadIdx.x; i < 4096; i += 256) {
        int j = i >> 6, d = i & 63;
        atw_t[j * 65 + d] = (j < 48) ? at_w[(j >> 3) * 512 + d * 8 + (j & 7)] : 0.f;
    }
    for (int i = threadIdx.x; i < 64; i += 256) atb_l[i] = (i < 48) ? at_b[i] : 0.f;
    for (int i = threadIdx.x; i < 80; i += 256) d2w_l[i] = (i < 49) ? d2_w[i] : 0.f;
    __syncthreads();
    int lane = threadIdx.x & 63;
    int wid = threadIdx.x >> 6;
    float d2w0 = d2w_l[0];
    float d2b0 = d2_b[0];
    float gcoef = d2w_l[1 + lane];  // zero for lane>=48
    for (int u = blockIdx.x * 4 + wid; u < U_NUM; u += gridDim.x * 4) {
        int eb = U_NUM * SEQL + u * SEQL;
        int id0 = edge_user[eb + 0], id1 = edge_user[eb + 1], id2 = edge_user[eb + 2],
            id3 = edge_user[eb + 3], id4 = edge_user[eb + 4];
        float c0 = ci_table[id0 * 64 + lane];
        float c1 = ci_table[id1 * 64 + lane];
        float c2 = ci_table[id2 * 64 + lane];
        float c3 = ci_table[id3 * 64 + lane];
        float c4 = ci_table[id4 * 64 + lane];
        float w0, w1, w2, w3, w4;
        w0 = w1 = w2 = w3 = w4 = atb_l[lane];
#pragma unroll 4
        for (int d = 0; d < 64; ++d) {
            float a = atw_t[lane * 65 + d];
            w0 = fmaf(__shfl(c0, d), a, w0);
            w1 = fmaf(__shfl(c1, d), a, w1);
            w2 = fmaf(__shfl(c2, d), a, w2);
            w3 = fmaf(__shfl(c3, d), a, w3);
            w4 = fmaf(__shfl(c4, d), a, w4);
        }
        float t0 = tanhf(w0), t1 = tanhf(w1), t2 = tanhf(w2), t3 = tanhf(w3), t4 = tanhf(w4);
        float m = fmaxf(fmaxf(fmaxf(t0, t1), fmaxf(t2, t3)), t4);
        float e0 = __expf(t0 - m), e1 = __expf(t1 - m), e2 = __expf(t2 - m),
              e3 = __expf(t3 - m), e4 = __expf(t4 - m);
        float ssum = e0 + e1 + e2 + e3 + e4;
        float gs = gcoef / ssum;
        float g0 = e0 * gs, g1 = e1 * gs, g2 = e2 * gs, g3 = e3 * gs, g4 = e4 * gs;
#pragma unroll
        for (int off = 32; off > 0; off >>= 1) {
            g0 += __shfl_xor(g0, off);
            g1 += __shfl_xor(g1, off);
            g2 += __shfl_xor(g2, off);
            g3 += __shfl_xor(g3, off);
            g4 += __shfl_xor(g4, off);
        }
        float r = fmaf(d2w0, ue[u * 64 + lane], d2b0);
        r = fmaf(g0, c0, r);
        r = fmaf(g1, c1, r);
        r = fmaf(g2, c2, r);
        r = fmaf(g3, c3, r);
        r = fmaf(g4, c4, r);
        uef[(size_t)u * 64 + lane] = r;
    }
}

// 16 users per block: uef(64) -> h1(256) -> h2(128) -> out(120), + ci2sum@d1_w folded in
__global__ __launch_bounds__(256) void k_mlp(const int* __restrict__ edge_user, const float* __restrict__ ci2,
                                             const float* __restrict__ uefg,
                                             const float* __restrict__ w1, const float* __restrict__ b1,
                                             const float* __restrict__ w2, const float* __restrict__ b2,
                                             const float* __restrict__ w3, const float* __restrict__ b3,
                                             const float* __restrict__ dw, const float* __restrict__ db,
                                             float* __restrict__ out) {
    __shared__ float uef_t[64 * 16];   // [d][ul]
    __shared__ float ci2_t[64 * 16];   // [d][ul]
    __shared__ float h1_t[256 * 16];   // [j][ul]
    __shared__ float h2_t[128 * 16];   // [j][ul]
    __shared__ int ids[80];
    int t = threadIdx.x;
    int u0 = blockIdx.x * 16;
    if (t < 80) ids[t] = edge_user[U_NUM * SEQL + u0 * SEQL + t];
    __syncthreads();
    for (int i = t; i < 1024; i += 256) {
        int ul = i >> 6, d = i & 63;
        uef_t[d * 16 + ul] = uefg[(size_t)(u0 + ul) * 64 + d];
        const int* myids = &ids[ul * 5];
        float s = 0.f;
#pragma unroll
        for (int q = 0; q < 5; ++q) s += ci2[(size_t)myids[q] * 64 + d];
        ci2_t[d * 16 + ul] = s;
    }
    __syncthreads();
    {  // phase 1: h1 = relu(uef @ W1 + b1), j = t
        float acc[16];
        float bb = b1[t];
#pragma unroll
        for (int r = 0; r < 16; ++r) acc[r] = bb;
        for (int d = 0; d < 64; ++d) {
            float w = w1[d * 256 + t];
            const float4* up = (const float4*)&uef_t[d * 16];
            float4 a0 = up[0], a1 = up[1], a2 = up[2], a3 = up[3];
            acc[0] = fmaf(a0.x, w, acc[0]);  acc[1] = fmaf(a0.y, w, acc[1]);
            acc[2] = fmaf(a0.z, w, acc[2]);  acc[3] = fmaf(a0.w, w, acc[3]);
            acc[4] = fmaf(a1.x, w, acc[4]);  acc[5] = fmaf(a1.y, w, acc[5]);
            acc[6] = fmaf(a1.z, w, acc[6]);  acc[7] = fmaf(a1.w, w, acc[7]);
            acc[8] = fmaf(a2.x, w, acc[8]);  acc[9] = fmaf(a2.y, w, acc[9]);
            acc[10] = fmaf(a2.z, w, acc[10]); acc[11] = fmaf(a2.w, w, acc[11]);
            acc[12] = fmaf(a3.x, w, acc[12]); acc[13] = fmaf(a3.y, w, acc[13]);
            acc[14] = fmaf(a3.z, w, acc[14]); acc[15] = fmaf(a3.w, w, acc[15]);
        }
        float4* hp = (float4*)&h1_t[t * 16];
        hp[0] = make_float4(fmaxf(acc[0], 0.f), fmaxf(acc[1], 0.f), fmaxf(acc[2], 0.f), fmaxf(acc[3], 0.f));
        hp[1] = make_float4(fmaxf(acc[4], 0.f), fmaxf(acc[5], 0.f), fmaxf(acc[6], 0.f), fmaxf(acc[7], 0.f));
        hp[2] = make_float4(fmaxf(acc[8], 0.f), fmaxf(acc[9], 0.f), fmaxf(acc[10], 0.f), fmaxf(acc[11], 0.f));
        hp[3] = make_float4(fmaxf(acc[12], 0.f), fmaxf(acc[13], 0.f), fmaxf(acc[14], 0.f), fmaxf(acc[15], 0.f));
    }
    __syncthreads();
    {  // phase 2: h2 = relu(h1 @ W2 + b2), j = t&127, half of users per thread-group
        int j = t & 127, ug = t >> 7;
        float acc[8];
        float bb = b2[j];
#pragma unroll
        for (int r = 0; r < 8; ++r) acc[r] = bb;
        for (int d = 0; d < 256; ++d) {
            float w = w2[d * 128 + j];
            const float4* hp = (const float4*)&h1_t[d * 16 + ug * 8];
            float4 a0 = hp[0], a1 = hp[1];
            acc[0] = fmaf(a0.x, w, acc[0]); acc[1] = fmaf(a0.y, w, acc[1]);
            acc[2] = fmaf(a0.z, w, acc[2]); acc[3] = fmaf(a0.w, w, acc[3]);
            acc[4] = fmaf(a1.x, w, acc[4]); acc[5] = fmaf(a1.y, w, acc[5]);
            acc[6] = fmaf(a1.z, w, acc[6]); acc[7] = fmaf(a1.w, w, acc[7]);
        }
        float4* op = (float4*)&h2_t[j * 16 + ug * 8];
        op[0] = make_float4(fmaxf(acc[0], 0.f), fmaxf(acc[1], 0.f), fmaxf(acc[2], 0.f), fmaxf(acc[3], 0.f));
        op[1] = make_float4(fmaxf(acc[4], 0.f), fmaxf(acc[5], 0.f), fmaxf(acc[6], 0.f), fmaxf(acc[7], 0.f));
    }
    __syncthreads();
    if (t < 240) {  // phase 3: out = h2 @ W3 + b3 + ci2sum @ d1_w + 5*d1_b
        int ug = (t >= 120) ? 1 : 0;
        int j = t - ug * 120;
        float acc[8];
        float bb = b3[j] + 5.f * db[j];
#pragma unroll
        for (int r = 0; r < 8; ++r) acc[r] = bb;
        for (int d = 0; d < 128; ++d) {
            float w = w3[d * 120 + j];
            const float4* hp = (const float4*)&h2_t[d * 16 + ug * 8];
            float4 a0 = hp[0], a1 = hp[1];
            acc[0] = fmaf(a0.x, w, acc[0]); acc[1] = fmaf(a0.y, w, acc[1]);
            acc[2] = fmaf(a0.z, w, acc[2]); acc[3] = fmaf(a0.w, w, acc[3]);
            acc[4] = fmaf(a1.x, w, acc[4]); acc[5] = fmaf(a1.y, w, acc[5]);
            acc[6] = fmaf(a1.z, w, acc[6]); acc[7] = fmaf(a1.w, w, acc[7]);
        }
        for (int d = 0; d < 64; ++d) {
            float w = dw[d * 120 + j];
            const float4* cp = (const float4*)&ci2_t[d * 16 + ug * 8];
            float4 a0 = cp[0], a1 = cp[1];
            acc[0] = fmaf(a0.x, w, acc[0]); acc[1] = fmaf(a0.y, w, acc[1]);
            acc[2] = fmaf(a0.z, w, acc[2]); acc[3] = fmaf(a0.w, w, acc[3]);
            acc[4] = fmaf(a1.x, w, acc[4]); acc[5] = fmaf(a1.y, w, acc[5]);
            acc[6] = fmaf(a1.w == a1.w ? a1.w : 0.f, 0.f, acc[6]);  // placeholder removed below
            acc[6] = fmaf(a1.z, w, acc[6]); acc[7] = fmaf(a1.w, w, acc[7]);
        }
#pragma unroll
        for (int r = 0; r < 8; ++r)
            out[(size_t)(u0 + ug * 8 + r) * 120 + j] = acc[r];
    }
}

extern "C" void kernel_launch(void* const* d_in, const int* in_sizes, int n_in,
                              void* d_out, int out_size, void* d_ws, size_t ws_size,
                              hipStream_t stream) {
    const int* edge_user   = (const int*)d_in[0];
    const int* u_v_edge    = (const int*)d_in[2];
    const float* user_table = (const float*)d_in[4];
    const float* ci_table   = (const float*)d_in[5];
    const float* ci_table2  = (const float*)d_in[6];
    const float* gcn1_w = (const float*)d_in[7];
    const float* gcn1_b = (const float*)d_in[8];
    const float* gcn2_w = (const float*)d_in[9];
    const float* gcn2_b = (const float*)d_in[10];
    const float* at_w = (const float*)d_in[11];
    const float* at_b = (const float*)d_in[12];
    const float* d2_w = (const float*)d_in[13];
    const float* d2_b = (const float*)d_in[14];
    const float* d1u_w = (const float*)d_in[15];
    const float* d1u_b = (const float*)d_in[16];
    const float* d2u_w = (const float*)d_in[17];
    const float* d2u_b = (const float*)d_in[18];
    const float* d3u_w = (const float*)d_in[19];
    const float* d3u_b = (const float*)d_in[20];
    const float* d1_w = (const float*)d_in[21];
    const float* d1_b = (const float*)d_in[22];
    float* out = (float*)d_out;
    char* ws = (char*)d_ws;

    int* deg       = (int*)(ws + OFF_DEG);
    int* cursor    = (int*)(ws + OFF_CURSOR);
    int* row_start = (int*)(ws + OFF_ROWSTART);
    float* dinv    = (float*)(ws + OFF_DINV);
    int* bsum      = (int*)(ws + OFF_BSUM);
    int* csr       = (int*)(ws + OFF_CSR);
    float* A       = (float*)(ws + OFF_A);
    float* B       = (float*)(ws + OFF_B);

    hipMemsetAsync(ws, 0, 800000, stream);  // deg + cursor
    k_count<<<6250, 256, 0, stream>>>(u_v_edge, deg);
    k_dinv<<<391, 256, 0, stream>>>(deg, dinv);
    k_scanA<<<98, 1024, 0, stream>>>(deg, bsum);
    k_scanB<<<1, 64, 0, stream>>>(bsum, 98);
    k_scanC<<<98, 1024, 0, stream>>>(deg, bsum, row_start);
    k_fill<<<6250, 256, 0, stream>>>(u_v_edge, row_start, cursor, csr);

    // GCN layer 1: A = user_table @ W1 ; B = A*dinv^2 + b1 ; B += gather
    k_gemm64<<<1024, 256, 0, stream>>>(user_table, gcn1_w, A, 0);
    k_init<<<6250, 256, 0, stream>>>((const float4*)A, dinv, gcn1_b, (float4*)B);
    k_gather<<<25000, 256, 0, stream>>>(A, dinv, row_start, csr, B);
    // GCN layer 2: A = relu(B) @ W2 ; B = A*dinv^2 + b2 ; B += gather
    k_gemm64<<<1024, 256, 0, stream>>>(B, gcn2_w, A, 1);
    k_init<<<6250, 256, 0, stream>>>((const float4*)A, dinv, gcn2_b, (float4*)B);
    k_gather<<<25000, 256, 0, stream>>>(A, dinv, row_start, csr, B);

    // attention -> uef into A (reads ue = B)
    k_attn<<<2048, 256, 0, stream>>>(edge_user, ci_table, at_w, at_b, d2_w, d2_b, B, A);
    // fused MLP + score2
    k_mlp<<<6250, 256, 0, stream>>>(edge_user, ci_table2, A,
                                    d1u_w, d1u_b, d2u_w, d2u_b, d3u_w, d3u_b, d1_w, d1_b, out);
}

// Round 2
// 933.751 us; speedup vs baseline: 1.3837x; 1.3837x over previous
//
#include <hip/hip_runtime.h>

#define U_NUM 100000
#define NE    1600000
#define SEQL  5

// ws layout (bytes)
#define OFF_DEG      0UL         // int[100000]
#define OFF_CURSOR   400000UL    // int[100000]
#define OFF_ROWSTART 800000UL    // int[100001]
#define OFF_DINV     1200016UL   // float[100000]
#define OFF_BSUM     1600016UL   // int[128]
#define OFF_CSR      1600528UL   // int[1600000]
#define OFF_A        8000528UL   // float[6400000]
#define OFF_B        33600528UL  // float[6400000]  (end 59200528)

__device__ __forceinline__ float rd_lane(float v, int l) {
    return __int_as_float(__builtin_amdgcn_readlane(__float_as_int(v), l));
}

__global__ __launch_bounds__(256) void k_count(const int* __restrict__ edge, int* __restrict__ deg) {
    int e = blockIdx.x * 256 + threadIdx.x;
    atomicAdd(&deg[edge[NE + e]], 1);
}

__global__ __launch_bounds__(256) void k_dinv(const int* __restrict__ deg, float* __restrict__ dinv) {
    int i = blockIdx.x * 256 + threadIdx.x;
    if (i < U_NUM) dinv[i] = rsqrtf((float)(deg[i] + 1));
}

__global__ __launch_bounds__(1024) void k_scanA(const int* __restrict__ deg, int* __restrict__ bsum) {
    __shared__ int sm[1024];
    int i = blockIdx.x * 1024 + threadIdx.x;
    sm[threadIdx.x] = (i < U_NUM) ? deg[i] : 0;
    __syncthreads();
    for (int off = 512; off > 0; off >>= 1) {
        if (threadIdx.x < off) sm[threadIdx.x] += sm[threadIdx.x + off];
        __syncthreads();
    }
    if (threadIdx.x == 0) bsum[blockIdx.x] = sm[0];
}

__global__ void k_scanB(int* bsum, int nb) {
    if (threadIdx.x == 0) {
        int acc = 0;
        for (int b = 0; b < nb; ++b) { int v = bsum[b]; bsum[b] = acc; acc += v; }
    }
}

__global__ __launch_bounds__(1024) void k_scanC(const int* __restrict__ deg, const int* __restrict__ bsum,
                                                int* __restrict__ row_start) {
    __shared__ int sm[1024];
    int t = threadIdx.x;
    int i = blockIdx.x * 1024 + t;
    int v = (i < U_NUM) ? deg[i] : 0;
    sm[t] = v;
    __syncthreads();
    for (int off = 1; off < 1024; off <<= 1) {
        int x = (t >= off) ? sm[t - off] : 0;
        __syncthreads();
        sm[t] += x;
        __syncthreads();
    }
    int incl = sm[t];
    int base = bsum[blockIdx.x];
    if (i < U_NUM) row_start[i] = base + incl - v;
    if (i == U_NUM - 1) row_start[U_NUM] = base + incl;
}

__global__ __launch_bounds__(256) void k_fill(const int* __restrict__ edge, const int* __restrict__ row_start,
                                              int* __restrict__ cursor, int* __restrict__ csr) {
    int e = blockIdx.x * 256 + threadIdx.x;
    int dst = edge[NE + e];
    int pos = row_start[dst] + atomicAdd(&cursor[dst], 1);
    csr[pos] = edge[e];
}

// out[r][d] = sum_k relu?(x[r][k]) * W[k][d]; lane=d holds W column d in registers,
// x[r][k] broadcast via v_readlane (VALU pipe, no ds_bpermute)
__global__ __launch_bounds__(256) void k_gemm64(const float* __restrict__ x, const float* __restrict__ w,
                                                float* __restrict__ out, int relu_in) {
    int lane = threadIdx.x & 63, wid = threadIdx.x >> 6;
    float wr[64];
#pragma unroll
    for (int k = 0; k < 64; ++k) wr[k] = w[k * 64 + lane];
    for (int r = blockIdx.x * 4 + wid; r < U_NUM; r += gridDim.x * 4) {
        float xr = x[r * 64 + lane];
        if (relu_in) xr = fmaxf(xr, 0.f);
        float acc0 = 0.f, acc1 = 0.f;
#pragma unroll
        for (int k = 0; k < 64; k += 2) {
            acc0 = fmaf(rd_lane(xr, k), wr[k], acc0);
            acc1 = fmaf(rd_lane(xr, k + 1), wr[k + 1], acc1);
        }
        out[r * 64 + lane] = acc0 + acc1;
    }
}

// per dst node (one wave each): out[i] = x[i]*dinv[i]^2 + bias + sum_{e} x[src]*dinv[i]*dinv[src]
__global__ __launch_bounds__(256) void k_gather(const float* __restrict__ xw, const float* __restrict__ dinv,
                                                const int* __restrict__ row_start, const int* __restrict__ csr,
                                                const float* __restrict__ bias, float* __restrict__ outb) {
    int i = blockIdx.x * 4 + (threadIdx.x >> 6);
    int lane = threadIdx.x & 63;
    int s0 = row_start[i], s1 = row_start[i + 1];
    float di = dinv[i];
    float acc = fmaf(xw[(size_t)i * 64 + lane], di * di, bias[lane]);
    for (int e = s0; e < s1; ++e) {
        int s = csr[e];
        acc = fmaf(xw[(size_t)s * 64 + lane], di * dinv[s], acc);
    }
    outb[(size_t)i * 64 + lane] = acc;
}

// per user (one wave each): attention -> gamma[5] -> uef[64]. No LDS; at_w row per lane
// in registers; ci broadcasts via v_readlane.
__global__ __launch_bounds__(256) void k_attn(const int* __restrict__ edge_user, const float* __restrict__ ci_table,
                                              const float* __restrict__ at_w, const float* __restrict__ at_b,
                                              const float* __restrict__ d2_w, const float* __restrict__ d2_b,
                                              const float* __restrict__ ue, float* __restrict__ uef) {
    int lane = threadIdx.x & 63;
    int wid = threadIdx.x >> 6;
    bool act = lane < 48;
    int h = lane >> 3, k7 = lane & 7;
    float atw_r[64];
#pragma unroll
    for (int d = 0; d < 64; ++d)
        atw_r[d] = act ? at_w[h * 512 + d * 8 + k7] : 0.f;   // at_w[h][d][k]
    float atb = act ? at_b[lane] : 0.f;                       // at_b[h][k], j=h*8+k=lane
    float gcoef = act ? d2_w[1 + lane] : 0.f;
    float d2w0 = d2_w[0];
    float d2b0 = d2_b[0];
    for (int u = blockIdx.x * 4 + wid; u < U_NUM; u += gridDim.x * 4) {
        int eb = U_NUM * SEQL + u * SEQL;
        int id0 = edge_user[eb + 0], id1 = edge_user[eb + 1], id2 = edge_user[eb + 2],
            id3 = edge_user[eb + 3], id4 = edge_user[eb + 4];
        float c0 = ci_table[(size_t)id0 * 64 + lane];
        float c1 = ci_table[(size_t)id1 * 64 + lane];
        float c2 = ci_table[(size_t)id2 * 64 + lane];
        float c3 = ci_table[(size_t)id3 * 64 + lane];
        float c4 = ci_table[(size_t)id4 * 64 + lane];
        float w0, w1, w2, w3, w4;
        w0 = w1 = w2 = w3 = w4 = atb;
#pragma unroll
        for (int d = 0; d < 64; ++d) {
            float a = atw_r[d];
            w0 = fmaf(rd_lane(c0, d), a, w0);
            w1 = fmaf(rd_lane(c1, d), a, w1);
            w2 = fmaf(rd_lane(c2, d), a, w2);
            w3 = fmaf(rd_lane(c3, d), a, w3);
            w4 = fmaf(rd_lane(c4, d), a, w4);
        }
        // tanh via exp: t = 1 - 2/(e^{2w}+1)
        float t0 = 1.f - __fdividef(2.f, __expf(2.f * w0) + 1.f);
        float t1 = 1.f - __fdividef(2.f, __expf(2.f * w1) + 1.f);
        float t2 = 1.f - __fdividef(2.f, __expf(2.f * w2) + 1.f);
        float t3 = 1.f - __fdividef(2.f, __expf(2.f * w3) + 1.f);
        float t4 = 1.f - __fdividef(2.f, __expf(2.f * w4) + 1.f);
        float m = fmaxf(fmaxf(fmaxf(t0, t1), fmaxf(t2, t3)), t4);
        float e0 = __expf(t0 - m), e1 = __expf(t1 - m), e2 = __expf(t2 - m),
              e3 = __expf(t3 - m), e4 = __expf(t4 - m);
        float gs = __fdividef(gcoef, e0 + e1 + e2 + e3 + e4);
        float g0 = e0 * gs, g1 = e1 * gs, g2 = e2 * gs, g3 = e3 * gs, g4 = e4 * gs;
#pragma unroll
        for (int off = 32; off > 0; off >>= 1) {
            g0 += __shfl_xor(g0, off);
            g1 += __shfl_xor(g1, off);
            g2 += __shfl_xor(g2, off);
            g3 += __shfl_xor(g3, off);
            g4 += __shfl_xor(g4, off);
        }
        float r = fmaf(d2w0, ue[(size_t)u * 64 + lane], d2b0);
        r = fmaf(g0, c0, r);
        r = fmaf(g1, c1, r);
        r = fmaf(g2, c2, r);
        r = fmaf(g3, c3, r);
        r = fmaf(g4, c4, r);
        uef[(size_t)u * 64 + lane] = r;
    }
}

// 16 users per block: uef(64) -> h1(256) -> h2(128) -> out(120), + ci2sum@d1_w folded in
__global__ __launch_bounds__(256) void k_mlp(const int* __restrict__ edge_user, const float* __restrict__ ci2,
                                             const float* __restrict__ uefg,
                                             const float* __restrict__ w1, const float* __restrict__ b1,
                                             const float* __restrict__ w2, const float* __restrict__ b2,
                                             const float* __restrict__ w3, const float* __restrict__ b3,
                                             const float* __restrict__ dw, const float* __restrict__ db,
                                             float* __restrict__ out) {
    __shared__ float uef_t[64 * 16];   // [d][ul]
    __shared__ float ci2_t[64 * 16];   // [d][ul]
    __shared__ float h1_t[256 * 16];   // [j][ul]
    __shared__ float h2_t[128 * 16];   // [j][ul]
    __shared__ int ids[80];
    int t = threadIdx.x;
    int u0 = blockIdx.x * 16;
    if (t < 80) ids[t] = edge_user[U_NUM * SEQL + u0 * SEQL + t];
    __syncthreads();
    for (int i = t; i < 1024; i += 256) {
        int ul = i >> 6, d = i & 63;
        uef_t[d * 16 + ul] = uefg[(size_t)(u0 + ul) * 64 + d];
        const int* myids = &ids[ul * 5];
        float s = 0.f;
#pragma unroll
        for (int q = 0; q < 5; ++q) s += ci2[(size_t)myids[q] * 64 + d];
        ci2_t[d * 16 + ul] = s;
    }
    __syncthreads();
    {  // phase 1: h1 = relu(uef @ W1 + b1), j = t
        float acc[16];
        float bb = b1[t];
#pragma unroll
        for (int r = 0; r < 16; ++r) acc[r] = bb;
        for (int d = 0; d < 64; ++d) {
            float w = w1[d * 256 + t];
            const float4* up = (const float4*)&uef_t[d * 16];
            float4 a0 = up[0], a1 = up[1], a2 = up[2], a3 = up[3];
            acc[0] = fmaf(a0.x, w, acc[0]);  acc[1] = fmaf(a0.y, w, acc[1]);
            acc[2] = fmaf(a0.z, w, acc[2]);  acc[3] = fmaf(a0.w, w, acc[3]);
            acc[4] = fmaf(a1.x, w, acc[4]);  acc[5] = fmaf(a1.y, w, acc[5]);
            acc[6] = fmaf(a1.z, w, acc[6]);  acc[7] = fmaf(a1.w, w, acc[7]);
            acc[8] = fmaf(a2.x, w, acc[8]);  acc[9] = fmaf(a2.y, w, acc[9]);
            acc[10] = fmaf(a2.z, w, acc[10]); acc[11] = fmaf(a2.w, w, acc[11]);
            acc[12] = fmaf(a3.x, w, acc[12]); acc[13] = fmaf(a3.y, w, acc[13]);
            acc[14] = fmaf(a3.z, w, acc[14]); acc[15] = fmaf(a3.w, w, acc[15]);
        }
        float4* hp = (float4*)&h1_t[t * 16];
        hp[0] = make_float4(fmaxf(acc[0], 0.f), fmaxf(acc[1], 0.f), fmaxf(acc[2], 0.f), fmaxf(acc[3], 0.f));
        hp[1] = make_float4(fmaxf(acc[4], 0.f), fmaxf(acc[5], 0.f), fmaxf(acc[6], 0.f), fmaxf(acc[7], 0.f));
        hp[2] = make_float4(fmaxf(acc[8], 0.f), fmaxf(acc[9], 0.f), fmaxf(acc[10], 0.f), fmaxf(acc[11], 0.f));
        hp[3] = make_float4(fmaxf(acc[12], 0.f), fmaxf(acc[13], 0.f), fmaxf(acc[14], 0.f), fmaxf(acc[15], 0.f));
    }
    __syncthreads();
    {  // phase 2: h2 = relu(h1 @ W2 + b2)
        int j = t & 127, ug = t >> 7;
        float acc[8];
        float bb = b2[j];
#pragma unroll
        for (int r = 0; r < 8; ++r) acc[r] = bb;
        for (int d = 0; d < 256; ++d) {
            float w = w2[d * 128 + j];
            const float4* hp = (const float4*)&h1_t[d * 16 + ug * 8];
            float4 a0 = hp[0], a1 = hp[1];
            acc[0] = fmaf(a0.x, w, acc[0]); acc[1] = fmaf(a0.y, w, acc[1]);
            acc[2] = fmaf(a0.z, w, acc[2]); acc[3] = fmaf(a0.w, w, acc[3]);
            acc[4] = fmaf(a1.x, w, acc[4]); acc[5] = fmaf(a1.y, w, acc[5]);
            acc[6] = fmaf(a1.z, w, acc[6]); acc[7] = fmaf(a1.w, w, acc[7]);
        }
        float4* op = (float4*)&h2_t[j * 16 + ug * 8];
        op[0] = make_float4(fmaxf(acc[0], 0.f), fmaxf(acc[1], 0.f), fmaxf(acc[2], 0.f), fmaxf(acc[3], 0.f));
        op[1] = make_float4(fmaxf(acc[4], 0.f), fmaxf(acc[5], 0.f), fmaxf(acc[6], 0.f), fmaxf(acc[7], 0.f));
    }
    __syncthreads();
    if (t < 240) {  // phase 3: out = h2 @ W3 + b3 + ci2sum @ d1_w + 5*d1_b
        int ug = (t >= 120) ? 1 : 0;
        int j = t - ug * 120;
        float acc[8];
        float bb = b3[j] + 5.f * db[j];
#pragma unroll
        for (int r = 0; r < 8; ++r) acc[r] = bb;
        for (int d = 0; d < 128; ++d) {
            float w = w3[d * 120 + j];
            const float4* hp = (const float4*)&h2_t[d * 16 + ug * 8];
            float4 a0 = hp[0], a1 = hp[1];
            acc[0] = fmaf(a0.x, w, acc[0]); acc[1] = fmaf(a0.y, w, acc[1]);
            acc[2] = fmaf(a0.z, w, acc[2]); acc[3] = fmaf(a0.w, w, acc[3]);
            acc[4] = fmaf(a1.x, w, acc[4]); acc[5] = fmaf(a1.y, w, acc[5]);
            acc[6] = fmaf(a1.z, w, acc[6]); acc[7] = fmaf(a1.w, w, acc[7]);
        }
        for (int d = 0; d < 64; ++d) {
            float w = dw[d * 120 + j];
            const float4* cp = (const float4*)&ci2_t[d * 16 + ug * 8];
            float4 a0 = cp[0], a1 = cp[1];
            acc[0] = fmaf(a0.x, w, acc[0]); acc[1] = fmaf(a0.y, w, acc[1]);
            acc[2] = fmaf(a0.z, w, acc[2]); acc[3] = fmaf(a0.w, w, acc[3]);
            acc[4] = fmaf(a1.x, w, acc[4]); acc[5] = fmaf(a1.y, w, acc[5]);
            acc[6] = fmaf(a1.z, w, acc[6]); acc[7] = fmaf(a1.w, w, acc[7]);
        }
#pragma unroll
        for (int r = 0; r < 8; ++r)
            out[(size_t)(u0 + ug * 8 + r) * 120 + j] = acc[r];
    }
}

extern "C" void kernel_launch(void* const* d_in, const int* in_sizes, int n_in,
                              void* d_out, int out_size, void* d_ws, size_t ws_size,
                              hipStream_t stream) {
    const int* edge_user   = (const int*)d_in[0];
    const int* u_v_edge    = (const int*)d_in[2];
    const float* user_table = (const float*)d_in[4];
    const float* ci_table   = (const float*)d_in[5];
    const float* ci_table2  = (const float*)d_in[6];
    const float* gcn1_w = (const float*)d_in[7];
    const float* gcn1_b = (const float*)d_in[8];
    const float* gcn2_w = (const float*)d_in[9];
    const float* gcn2_b = (const float*)d_in[10];
    const float* at_w = (const float*)d_in[11];
    const float* at_b = (const float*)d_in[12];
    const float* d2_w = (const float*)d_in[13];
    const float* d2_b = (const float*)d_in[14];
    const float* d1u_w = (const float*)d_in[15];
    const float* d1u_b = (const float*)d_in[16];
    const float* d2u_w = (const float*)d_in[17];
    const float* d2u_b = (const float*)d_in[18];
    const float* d3u_w = (const float*)d_in[19];
    const float* d3u_b = (const float*)d_in[20];
    const float* d1_w = (const float*)d_in[21];
    const float* d1_b = (const float*)d_in[22];
    float* out = (float*)d_out;
    char* ws = (char*)d_ws;

    int* deg       = (int*)(ws + OFF_DEG);
    int* row_start = (int*)(ws + OFF_ROWSTART);
    float* dinv    = (float*)(ws + OFF_DINV);
    int* bsum      = (int*)(ws + OFF_BSUM);
    int* cursor    = (int*)(ws + OFF_CURSOR);
    int* csr       = (int*)(ws + OFF_CSR);
    float* A       = (float*)(ws + OFF_A);
    float* B       = (float*)(ws + OFF_B);

    hipMemsetAsync(ws, 0, 800000, stream);  // deg + cursor
    k_count<<<6250, 256, 0, stream>>>(u_v_edge, deg);
    k_dinv<<<391, 256, 0, stream>>>(deg, dinv);
    k_scanA<<<98, 1024, 0, stream>>>(deg, bsum);
    k_scanB<<<1, 64, 0, stream>>>(bsum, 98);
    k_scanC<<<98, 1024, 0, stream>>>(deg, bsum, row_start);
    k_fill<<<6250, 256, 0, stream>>>(u_v_edge, row_start, cursor, csr);

    // GCN layer 1: A = user_table @ W1 ; B = A*dinv^2 + b1 + gather(A)
    k_gemm64<<<1024, 256, 0, stream>>>(user_table, gcn1_w, A, 0);
    k_gather<<<25000, 256, 0, stream>>>(A, dinv, row_start, csr, gcn1_b, B);
    // GCN layer 2: A = relu(B) @ W2 ; B = A*dinv^2 + b2 + gather(A)
    k_gemm64<<<1024, 256, 0, stream>>>(B, gcn2_w, A, 1);
    k_gather<<<25000, 256, 0, stream>>>(A, dinv, row_start, csr, gcn2_b, B);

    // attention -> uef into A (reads ue = B)
    k_attn<<<2048, 256, 0, stream>>>(edge_user, ci_table, at_w, at_b, d2_w, d2_b, B, A);
    // fused MLP + score2
    k_mlp<<<6250, 256, 0, stream>>>(edge_user, ci_table2, A,
                                    d1u_w, d1u_b, d2u_w, d2u_b, d3u_w, d3u_b, d1_w, d1_b, out);
}

// Round 3
// 700.391 us; speedup vs baseline: 1.8447x; 1.3332x over previous
//
#include <hip/hip_runtime.h>

#define U_NUM 100000
#define NE    1600000
#define SEQL  5

// ws layout (bytes)
#define OFF_DEG      0UL         // int[100000]
#define OFF_CURSOR   400000UL    // int[100000]
#define OFF_ROWSTART 800000UL    // int[100001]
#define OFF_DINV     1200016UL   // float[100000]
#define OFF_BSUM     1600016UL   // int[128]
#define OFF_CSR      1600528UL   // int[1600000]
#define OFF_A        8000528UL   // float[6400000]
#define OFF_B        33600528UL  // float[6400000]  (end 59200528)

typedef __attribute__((ext_vector_type(8))) short bf16x8;
typedef __attribute__((ext_vector_type(4))) float f32x4;

__device__ __forceinline__ float rd_lane(float v, int l) {
    return __int_as_float(__builtin_amdgcn_readlane(__float_as_int(v), l));
}

__device__ __forceinline__ short f2bf(float f) {
    unsigned u = __float_as_uint(f);
    unsigned r = (u + 0x7fffu + ((u >> 16) & 1u)) >> 16;
    return (short)r;
}

// swizzled byte offset within a row-major LDS tile (T2: XOR bits 4-6 by row&7)
__device__ __forceinline__ int swzo(int row, int bytecol, int rowstride) {
    return row * rowstride + (bytecol ^ ((row & 7) << 4));
}

__global__ __launch_bounds__(256) void k_count(const int* __restrict__ edge, int* __restrict__ deg) {
    int e = blockIdx.x * 256 + threadIdx.x;
    atomicAdd(&deg[edge[NE + e]], 1);
}

__global__ __launch_bounds__(256) void k_dinv(const int* __restrict__ deg, float* __restrict__ dinv) {
    int i = blockIdx.x * 256 + threadIdx.x;
    if (i < U_NUM) dinv[i] = rsqrtf((float)(deg[i] + 1));
}

__global__ __launch_bounds__(1024) void k_scanA(const int* __restrict__ deg, int* __restrict__ bsum) {
    __shared__ int sm[1024];
    int i = blockIdx.x * 1024 + threadIdx.x;
    sm[threadIdx.x] = (i < U_NUM) ? deg[i] : 0;
    __syncthreads();
    for (int off = 512; off > 0; off >>= 1) {
        if (threadIdx.x < off) sm[threadIdx.x] += sm[threadIdx.x + off];
        __syncthreads();
    }
    if (threadIdx.x == 0) bsum[blockIdx.x] = sm[0];
}

__global__ void k_scanB(int* bsum, int nb) {
    if (threadIdx.x == 0) {
        int acc = 0;
        for (int b = 0; b < nb; ++b) { int v = bsum[b]; bsum[b] = acc; acc += v; }
    }
}

__global__ __launch_bounds__(1024) void k_scanC(const int* __restrict__ deg, const int* __restrict__ bsum,
                                                int* __restrict__ row_start) {
    __shared__ int sm[1024];
    int t = threadIdx.x;
    int i = blockIdx.x * 1024 + t;
    int v = (i < U_NUM) ? deg[i] : 0;
    sm[t] = v;
    __syncthreads();
    for (int off = 1; off < 1024; off <<= 1) {
        int x = (t >= off) ? sm[t - off] : 0;
        __syncthreads();
        sm[t] += x;
        __syncthreads();
    }
    int incl = sm[t];
    int base = bsum[blockIdx.x];
    if (i < U_NUM) row_start[i] = base + incl - v;
    if (i == U_NUM - 1) row_start[U_NUM] = base + incl;
}

__global__ __launch_bounds__(256) void k_fill(const int* __restrict__ edge, const int* __restrict__ row_start,
                                              int* __restrict__ cursor, int* __restrict__ csr) {
    int e = blockIdx.x * 256 + threadIdx.x;
    int dst = edge[NE + e];
    int pos = row_start[dst] + atomicAdd(&cursor[dst], 1);
    csr[pos] = edge[e];
}

// out[r][d] = (sum_k relu?(x[r][k]) * W[k][d]) * scale[r]   (prescale by dinv)
__global__ __launch_bounds__(256) void k_gemm64(const float* __restrict__ x, const float* __restrict__ w,
                                                const float* __restrict__ scale,
                                                float* __restrict__ out, int relu_in) {
    int lane = threadIdx.x & 63, wid = threadIdx.x >> 6;
    float wr[64];
#pragma unroll
    for (int k = 0; k < 64; ++k) wr[k] = w[k * 64 + lane];
    for (int r = blockIdx.x * 4 + wid; r < U_NUM; r += gridDim.x * 4) {
        float xr = x[(size_t)r * 64 + lane];
        if (relu_in) xr = fmaxf(xr, 0.f);
        float acc0 = 0.f, acc1 = 0.f;
#pragma unroll
        for (int k = 0; k < 64; k += 2) {
            acc0 = fmaf(rd_lane(xr, k), wr[k], acc0);
            acc1 = fmaf(rd_lane(xr, k + 1), wr[k + 1], acc1);
        }
        out[(size_t)r * 64 + lane] = (acc0 + acc1) * scale[r];
    }
}

// per dst node (one wave): out[i] = (sum_{e} xs[src] + xs[i]) * dinv[i] + bias
// xs is prescaled by dinv[row]; 4-deep unrolled independent loads
__global__ __launch_bounds__(256) void k_gather(const float* __restrict__ xs, const float* __restrict__ dinv,
                                                const int* __restrict__ row_start, const int* __restrict__ csr,
                                                const float* __restrict__ bias, float* __restrict__ outb) {
    int i = blockIdx.x * 4 + (threadIdx.x >> 6);
    int lane = threadIdx.x & 63;
    int s0 = row_start[i], s1 = row_start[i + 1];
    float di = dinv[i];
    float self = xs[(size_t)i * 64 + lane];
    float acc0 = 0.f, acc1 = 0.f, acc2 = 0.f, acc3 = 0.f;
    int e = s0;
    for (; e + 4 <= s1; e += 4) {
        int sa = csr[e], sb = csr[e + 1], sc = csr[e + 2], sd = csr[e + 3];
        acc0 += xs[(size_t)sa * 64 + lane];
        acc1 += xs[(size_t)sb * 64 + lane];
        acc2 += xs[(size_t)sc * 64 + lane];
        acc3 += xs[(size_t)sd * 64 + lane];
    }
    for (; e < s1; ++e) acc0 += xs[(size_t)csr[e] * 64 + lane];
    outb[(size_t)i * 64 + lane] = fmaf((acc0 + acc1) + (acc2 + acc3) + self, di, bias[lane]);
}

// per user (one wave each): attention -> gamma[5] -> uef[64]
__global__ __launch_bounds__(256) void k_attn(const int* __restrict__ edge_user, const float* __restrict__ ci_table,
                                              const float* __restrict__ at_w, const float* __restrict__ at_b,
                                              const float* __restrict__ d2_w, const float* __restrict__ d2_b,
                                              const float* __restrict__ ue, float* __restrict__ uef) {
    int lane = threadIdx.x & 63;
    int wid = threadIdx.x >> 6;
    bool act = lane < 48;
    int h = lane >> 3, k7 = lane & 7;
    float atw_r[64];
#pragma unroll
    for (int d = 0; d < 64; ++d)
        atw_r[d] = act ? at_w[h * 512 + d * 8 + k7] : 0.f;   // at_w[h][d][k]
    float atb = act ? at_b[lane] : 0.f;
    float gcoef = act ? d2_w[1 + lane] : 0.f;
    float d2w0 = d2_w[0];
    float d2b0 = d2_b[0];
    for (int u = blockIdx.x * 4 + wid; u < U_NUM; u += gridDim.x * 4) {
        int eb = U_NUM * SEQL + u * SEQL;
        int id0 = edge_user[eb + 0], id1 = edge_user[eb + 1], id2 = edge_user[eb + 2],
            id3 = edge_user[eb + 3], id4 = edge_user[eb + 4];
        float c0 = ci_table[(size_t)id0 * 64 + lane];
        float c1 = ci_table[(size_t)id1 * 64 + lane];
        float c2 = ci_table[(size_t)id2 * 64 + lane];
        float c3 = ci_table[(size_t)id3 * 64 + lane];
        float c4 = ci_table[(size_t)id4 * 64 + lane];
        float w0, w1, w2, w3, w4;
        w0 = w1 = w2 = w3 = w4 = atb;
#pragma unroll
        for (int d = 0; d < 64; ++d) {
            float a = atw_r[d];
            w0 = fmaf(rd_lane(c0, d), a, w0);
            w1 = fmaf(rd_lane(c1, d), a, w1);
            w2 = fmaf(rd_lane(c2, d), a, w2);
            w3 = fmaf(rd_lane(c3, d), a, w3);
            w4 = fmaf(rd_lane(c4, d), a, w4);
        }
        // tanh(w) in [-1,1] -> exp safe without max subtraction
        float t0 = 1.f - __fdividef(2.f, __expf(2.f * w0) + 1.f);
        float t1 = 1.f - __fdividef(2.f, __expf(2.f * w1) + 1.f);
        float t2 = 1.f - __fdividef(2.f, __expf(2.f * w2) + 1.f);
        float t3 = 1.f - __fdividef(2.f, __expf(2.f * w3) + 1.f);
        float t4 = 1.f - __fdividef(2.f, __expf(2.f * w4) + 1.f);
        float e0 = __expf(t0), e1 = __expf(t1), e2 = __expf(t2), e3 = __expf(t3), e4 = __expf(t4);
        float gs = __fdividef(gcoef, e0 + e1 + e2 + e3 + e4);
        float g0 = e0 * gs, g1 = e1 * gs, g2 = e2 * gs, g3 = e3 * gs, g4 = e4 * gs;
#pragma unroll
        for (int off = 32; off > 0; off >>= 1) {
            g0 += __shfl_xor(g0, off);
            g1 += __shfl_xor(g1, off);
            g2 += __shfl_xor(g2, off);
            g3 += __shfl_xor(g3, off);
            g4 += __shfl_xor(g4, off);
        }
        float r = fmaf(d2w0, ue[(size_t)u * 64 + lane], d2b0);
        r = fmaf(g0, c0, r);
        r = fmaf(g1, c1, r);
        r = fmaf(g2, c2, r);
        r = fmaf(g3, c3, r);
        r = fmaf(g4, c4, r);
        uef[(size_t)u * 64 + lane] = r;
    }
}

// ---------------- MFMA MLP ----------------
// Persistent blocks, 64 users/tile. Weights as B-fragments in registers.
// Layer dims: 64 ->256 ->128 ->120(+ci2sum 64 as K-extension of last GEMM).
// mfma_f32_16x16x32_bf16: A row=l&15, k=(l>>4)*8+j; B col=l&15, same k; D col=l&15, row=(l>>4)*4+r.
#define N_TILES 1563

__global__ __launch_bounds__(256, 2) void k_mlp_mfma(
        const int* __restrict__ edge_user, const float* __restrict__ ci2,
        const float* __restrict__ uefg,
        const float* __restrict__ w1, const float* __restrict__ b1,
        const float* __restrict__ w2, const float* __restrict__ b2,
        const float* __restrict__ w3, const float* __restrict__ b3,
        const float* __restrict__ dw, const float* __restrict__ db,
        float* __restrict__ out) {
    __shared__ short Xa[64 * 64];     // 8KB  stride 128B, swizzled
    __shared__ short h1a[64 * 256];   // 32KB stride 512B, swizzled
    __shared__ short h2c[64 * 192];   // 24KB stride 384B, swizzled; cols 128..191 = ci2sum
    int t = threadIdx.x;
    int lane = t & 63, w = t >> 6;
    int l15 = lane & 15, lg = lane >> 4;

    // ---- load persistent weight B-fragments (once per block) ----
    bf16x8 wf1[8];   // [nt*2+ks]  cols w*64+nt*16+l15, K=64
#pragma unroll
    for (int nt = 0; nt < 4; ++nt)
#pragma unroll
        for (int ks = 0; ks < 2; ++ks) {
            int col = w * 64 + nt * 16 + l15;
            int kb = ks * 32 + lg * 8;
            bf16x8 f;
#pragma unroll
            for (int j = 0; j < 8; ++j) f[j] = f2bf(w1[(kb + j) * 256 + col]);
            wf1[nt * 2 + ks] = f;
        }
    bf16x8 wf2[16];  // [nt*8+ks]  cols w*32+nt*16+l15, K=256
#pragma unroll
    for (int nt = 0; nt < 2; ++nt)
#pragma unroll
        for (int ks = 0; ks < 8; ++ks) {
            int col = w * 32 + nt * 16 + l15;
            int kb = ks * 32 + lg * 8;
            bf16x8 f;
#pragma unroll
            for (int j = 0; j < 8; ++j) f[j] = f2bf(w2[(kb + j) * 128 + col]);
            wf2[nt * 8 + ks] = f;
        }
    bf16x8 wf3[12];  // [nt*6+ks]  cols w*32+nt*16+l15 (<120 else 0), K=192: 0..127=w3, 128..191=dw
#pragma unroll
    for (int nt = 0; nt < 2; ++nt)
#pragma unroll
        for (int ks = 0; ks < 6; ++ks) {
            int col = w * 32 + nt * 16 + l15;
            int kb = ks * 32 + lg * 8;
            bf16x8 f;
#pragma unroll
            for (int j = 0; j < 8; ++j) {
                int k = kb + j;
                float v = 0.f;
                if (col < 120) v = (k < 128) ? w3[k * 120 + col] : dw[(k - 128) * 120 + col];
                f[j] = f2bf(v);
            }
            wf3[nt * 6 + ks] = f;
        }
    float bias1[4], bias2[2], bias3[2];
#pragma unroll
    for (int nt = 0; nt < 4; ++nt) bias1[nt] = b1[w * 64 + nt * 16 + l15];
#pragma unroll
    for (int nt = 0; nt < 2; ++nt) {
        int col = w * 32 + nt * 16 + l15;
        bias2[nt] = b2[col];
        bias3[nt] = (col < 120) ? (b3[col] + 5.f * db[col]) : 0.f;
    }

    for (int tile = blockIdx.x; tile < N_TILES; tile += gridDim.x) {
        int u0 = tile * 64;
        // ---- load phase: Xa (uef->bf16) and Ca (ci2sum->bf16, h2c cols 128..191) ----
        {
            int ur = t >> 2, d0 = (t & 3) * 16;
            int u = u0 + ur;
            float xv[16];
            if (u < U_NUM) {
                const float4* up = (const float4*)(uefg + (size_t)u * 64 + d0);
#pragma unroll
                for (int q = 0; q < 4; ++q) {
                    float4 v = up[q];
                    xv[q * 4 + 0] = v.x; xv[q * 4 + 1] = v.y; xv[q * 4 + 2] = v.z; xv[q * 4 + 3] = v.w;
                }
            } else {
#pragma unroll
                for (int q = 0; q < 16; ++q) xv[q] = 0.f;
            }
            bf16x8 p0, p1;
#pragma unroll
            for (int j = 0; j < 8; ++j) { p0[j] = f2bf(xv[j]); p1[j] = f2bf(xv[8 + j]); }
            *(bf16x8*)((char*)Xa + swzo(ur, d0 * 2, 128)) = p0;
            *(bf16x8*)((char*)Xa + swzo(ur, d0 * 2 + 16, 128)) = p1;

            float cs[16];
#pragma unroll
            for (int q = 0; q < 16; ++q) cs[q] = 0.f;
            if (u < U_NUM) {
                const int* eb = edge_user + U_NUM * SEQL + u * SEQL;
#pragma unroll
                for (int q = 0; q < 5; ++q) {
                    const float4* cp = (const float4*)(ci2 + (size_t)eb[q] * 64 + d0);
#pragma unroll
                    for (int p = 0; p < 4; ++p) {
                        float4 v = cp[p];
                        cs[p * 4 + 0] += v.x; cs[p * 4 + 1] += v.y; cs[p * 4 + 2] += v.z; cs[p * 4 + 3] += v.w;
                    }
                }
            }
            bf16x8 q0, q1;
#pragma unroll
            for (int j = 0; j < 8; ++j) { q0[j] = f2bf(cs[j]); q1[j] = f2bf(cs[8 + j]); }
            *(bf16x8*)((char*)h2c + swzo(ur, 256 + d0 * 2, 384)) = q0;
            *(bf16x8*)((char*)h2c + swzo(ur, 256 + d0 * 2 + 16, 384)) = q1;
        }
        __syncthreads();
        // ---- phase 1: h1 = relu(X @ W1 + b1), N-split across waves ----
#pragma unroll
        for (int mt = 0; mt < 4; ++mt) {
            bf16x8 a0 = *(bf16x8*)((char*)Xa + swzo(mt * 16 + l15, lg * 16, 128));
            bf16x8 a1 = *(bf16x8*)((char*)Xa + swzo(mt * 16 + l15, 64 + lg * 16, 128));
#pragma unroll
            for (int nt = 0; nt < 4; ++nt) {
                f32x4 c = {0.f, 0.f, 0.f, 0.f};
                c = __builtin_amdgcn_mfma_f32_16x16x32_bf16(a0, wf1[nt * 2 + 0], c, 0, 0, 0);
                c = __builtin_amdgcn_mfma_f32_16x16x32_bf16(a1, wf1[nt * 2 + 1], c, 0, 0, 0);
                int col = w * 64 + nt * 16 + l15;
                float bb = bias1[nt];
#pragma unroll
                for (int r = 0; r < 4; ++r) {
                    int row = mt * 16 + lg * 4 + r;
                    *(short*)((char*)h1a + swzo(row, col * 2, 512)) = f2bf(fmaxf(c[r] + bb, 0.f));
                }
            }
        }
        __syncthreads();
        // ---- phase 2: h2 = relu(h1 @ W2 + b2) ----
#pragma unroll
        for (int mt = 0; mt < 4; ++mt) {
            bf16x8 af[8];
#pragma unroll
            for (int ks = 0; ks < 8; ++ks)
                af[ks] = *(bf16x8*)((char*)h1a + swzo(mt * 16 + l15, ks * 64 + lg * 16, 512));
#pragma unroll
            for (int nt = 0; nt < 2; ++nt) {
                f32x4 c = {0.f, 0.f, 0.f, 0.f};
#pragma unroll
                for (int ks = 0; ks < 8; ++ks)
                    c = __builtin_amdgcn_mfma_f32_16x16x32_bf16(af[ks], wf2[nt * 8 + ks], c, 0, 0, 0);
                int col = w * 32 + nt * 16 + l15;
                float bb = bias2[nt];
#pragma unroll
                for (int r = 0; r < 4; ++r) {
                    int row = mt * 16 + lg * 4 + r;
                    *(short*)((char*)h2c + swzo(row, col * 2, 384)) = f2bf(fmaxf(c[r] + bb, 0.f));
                }
            }
        }
        __syncthreads();
        // ---- phase 3: out = [h2|ci2sum] @ [W3;dw] + b3 + 5*db ----
#pragma unroll
        for (int mt = 0; mt < 4; ++mt) {
            bf16x8 af[6];
#pragma unroll
            for (int ks = 0; ks < 6; ++ks)
                af[ks] = *(bf16x8*)((char*)h2c + swzo(mt * 16 + l15, ks * 64 + lg * 16, 384));
#pragma unroll
            for (int nt = 0; nt < 2; ++nt) {
                f32x4 c = {0.f, 0.f, 0.f, 0.f};
#pragma unroll
                for (int ks = 0; ks < 6; ++ks)
                    c = __builtin_amdgcn_mfma_f32_16x16x32_bf16(af[ks], wf3[nt * 6 + ks], c, 0, 0, 0);
                int col = w * 32 + nt * 16 + l15;
                float bb = bias3[nt];
                if (col < 120) {
#pragma unroll
                    for (int r = 0; r < 4; ++r) {
                        int u = u0 + mt * 16 + lg * 4 + r;
                        if (u < U_NUM) out[(size_t)u * 120 + col] = c[r] + bb;
                    }
                }
            }
        }
        __syncthreads();
    }
}

extern "C" void kernel_launch(void* const* d_in, const int* in_sizes, int n_in,
                              void* d_out, int out_size, void* d_ws, size_t ws_size,
                              hipStream_t stream) {
    const int* edge_user   = (const int*)d_in[0];
    const int* u_v_edge    = (const int*)d_in[2];
    const float* user_table = (const float*)d_in[4];
    const float* ci_table   = (const float*)d_in[5];
    const float* ci_table2  = (const float*)d_in[6];
    const float* gcn1_w = (const float*)d_in[7];
    const float* gcn1_b = (const float*)d_in[8];
    const float* gcn2_w = (const float*)d_in[9];
    const float* gcn2_b = (const float*)d_in[10];
    const float* at_w = (const float*)d_in[11];
    const float* at_b = (const float*)d_in[12];
    const float* d2_w = (const float*)d_in[13];
    const float* d2_b = (const float*)d_in[14];
    const float* d1u_w = (const float*)d_in[15];
    const float* d1u_b = (const float*)d_in[16];
    const float* d2u_w = (const float*)d_in[17];
    const float* d2u_b = (const float*)d_in[18];
    const float* d3u_w = (const float*)d_in[19];
    const float* d3u_b = (const float*)d_in[20];
    const float* d1_w = (const float*)d_in[21];
    const float* d1_b = (const float*)d_in[22];
    float* out = (float*)d_out;
    char* ws = (char*)d_ws;

    int* deg       = (int*)(ws + OFF_DEG);
    int* cursor    = (int*)(ws + OFF_CURSOR);
    int* row_start = (int*)(ws + OFF_ROWSTART);
    float* dinv    = (float*)(ws + OFF_DINV);
    int* bsum      = (int*)(ws + OFF_BSUM);
    int* csr       = (int*)(ws + OFF_CSR);
    float* A       = (float*)(ws + OFF_A);
    float* B       = (float*)(ws + OFF_B);

    hipMemsetAsync(ws, 0, 800000, stream);  // deg + cursor
    k_count<<<6250, 256, 0, stream>>>(u_v_edge, deg);
    k_dinv<<<391, 256, 0, stream>>>(deg, dinv);
    k_scanA<<<98, 1024, 0, stream>>>(deg, bsum);
    k_scanB<<<1, 64, 0, stream>>>(bsum, 98);
    k_scanC<<<98, 1024, 0, stream>>>(deg, bsum, row_start);
    k_fill<<<6250, 256, 0, stream>>>(u_v_edge, row_start, cursor, csr);

    // GCN layer 1: A = (user_table @ W1) * dinv ; B = (gather(A)+A)*dinv + b1
    k_gemm64<<<1024, 256, 0, stream>>>(user_table, gcn1_w, dinv, A, 0);
    k_gather<<<25000, 256, 0, stream>>>(A, dinv, row_start, csr, gcn1_b, B);
    // GCN layer 2
    k_gemm64<<<1024, 256, 0, stream>>>(B, gcn2_w, dinv, A, 1);
    k_gather<<<25000, 256, 0, stream>>>(A, dinv, row_start, csr, gcn2_b, B);

    // attention -> uef into A (reads ue = B)
    k_attn<<<2048, 256, 0, stream>>>(edge_user, ci_table, at_w, at_b, d2_w, d2_b, B, A);
    // fused MFMA MLP + score2
    k_mlp_mfma<<<512, 256, 0, stream>>>(edge_user, ci_table2, A,
                                        d1u_w, d1u_b, d2u_w, d2u_b, d3u_w, d3u_b, d1_w, d1_b, out);
}

// Round 4
// 565.112 us; speedup vs baseline: 2.2863x; 1.2394x over previous
//
#include <hip/hip_runtime.h>

#define U_NUM 100000
#define NE    1600000
#define SEQL  5

// ws layout (bytes)
#define OFF_DEG      0UL         // int[100000]
#define OFF_CURSOR   400000UL    // int[100000]
#define OFF_ROWSTART 800000UL    // int[100001]
#define OFF_DINV     1200016UL   // float[100000]
#define OFF_BSUM     1600016UL   // int[128]
#define OFF_CSR      1600528UL   // int[1600000]
#define OFF_XS       8000528UL   // bf16-packed uint[3200000] (12.8MB); later uef bf16 overlays
#define OFF_B        20800528UL  // float[6400000] (25.6MB)  (end 46400528)

typedef __attribute__((ext_vector_type(8))) short bf16x8;
typedef __attribute__((ext_vector_type(4))) float f32x4;

__device__ __forceinline__ float rd_lane(float v, int l) {
    return __int_as_float(__builtin_amdgcn_readlane(__float_as_int(v), l));
}

__device__ __forceinline__ short f2bf(float f) {
    unsigned u = __float_as_uint(f);
    unsigned r = (u + 0x7fffu + ((u >> 16) & 1u)) >> 16;
    return (short)r;
}

__device__ __forceinline__ unsigned pk2(float a, float b) {
    return ((unsigned)(unsigned short)f2bf(a)) | (((unsigned)(unsigned short)f2bf(b)) << 16);
}

__device__ __forceinline__ float bflo(unsigned p) { return __uint_as_float(p << 16); }
__device__ __forceinline__ float bfhi(unsigned p) { return __uint_as_float(p & 0xffff0000u); }

// swizzled byte offset within a row-major LDS tile (T2: XOR bits 4-6 by row&7)
__device__ __forceinline__ int swzo(int row, int bytecol, int rowstride) {
    return row * rowstride + (bytecol ^ ((row & 7) << 4));
}

__global__ __launch_bounds__(256) void k_count(const int* __restrict__ edge, int* __restrict__ deg) {
    int e = blockIdx.x * 256 + threadIdx.x;
    atomicAdd(&deg[edge[NE + e]], 1);
}

__global__ __launch_bounds__(256) void k_dinv(const int* __restrict__ deg, float* __restrict__ dinv) {
    int i = blockIdx.x * 256 + threadIdx.x;
    if (i < U_NUM) dinv[i] = rsqrtf((float)(deg[i] + 1));
}

__global__ __launch_bounds__(1024) void k_scanA(const int* __restrict__ deg, int* __restrict__ bsum) {
    __shared__ int sm[1024];
    int i = blockIdx.x * 1024 + threadIdx.x;
    sm[threadIdx.x] = (i < U_NUM) ? deg[i] : 0;
    __syncthreads();
    for (int off = 512; off > 0; off >>= 1) {
        if (threadIdx.x < off) sm[threadIdx.x] += sm[threadIdx.x + off];
        __syncthreads();
    }
    if (threadIdx.x == 0) bsum[blockIdx.x] = sm[0];
}

__global__ void k_scanB(int* bsum, int nb) {
    if (threadIdx.x == 0) {
        int acc = 0;
        for (int b = 0; b < nb; ++b) { int v = bsum[b]; bsum[b] = acc; acc += v; }
    }
}

__global__ __launch_bounds__(1024) void k_scanC(const int* __restrict__ deg, const int* __restrict__ bsum,
                                                int* __restrict__ row_start) {
    __shared__ int sm[1024];
    int t = threadIdx.x;
    int i = blockIdx.x * 1024 + t;
    int v = (i < U_NUM) ? deg[i] : 0;
    sm[t] = v;
    __syncthreads();
    for (int off = 1; off < 1024; off <<= 1) {
        int x = (t >= off) ? sm[t - off] : 0;
        __syncthreads();
        sm[t] += x;
        __syncthreads();
    }
    int incl = sm[t];
    int base = bsum[blockIdx.x];
    if (i < U_NUM) row_start[i] = base + incl - v;
    if (i == U_NUM - 1) row_start[U_NUM] = base + incl;
}

__global__ __launch_bounds__(256) void k_fill(const int* __restrict__ edge, const int* __restrict__ row_start,
                                              int* __restrict__ cursor, int* __restrict__ csr) {
    int e = blockIdx.x * 256 + threadIdx.x;
    int dst = edge[NE + e];
    int pos = row_start[dst] + atomicAdd(&cursor[dst], 1);
    csr[pos] = edge[e];
}

// out[r][d] = (sum_k relu?(x[r][k]) * W[k][d]) * scale[r], packed to bf16 rows (32 uints)
__global__ __launch_bounds__(256) void k_gemm64b(const float* __restrict__ x, const float* __restrict__ w,
                                                 const float* __restrict__ scale,
                                                 unsigned* __restrict__ outb, int relu_in) {
    int lane = threadIdx.x & 63, wid = threadIdx.x >> 6;
    float wr[64];
#pragma unroll
    for (int k = 0; k < 64; ++k) wr[k] = w[k * 64 + lane];
    for (int r = blockIdx.x * 4 + wid; r < U_NUM; r += gridDim.x * 4) {
        float xr = x[(size_t)r * 64 + lane];
        if (relu_in) xr = fmaxf(xr, 0.f);
        float acc0 = 0.f, acc1 = 0.f;
#pragma unroll
        for (int k = 0; k < 64; k += 2) {
            acc0 = fmaf(rd_lane(xr, k), wr[k], acc0);
            acc1 = fmaf(rd_lane(xr, k + 1), wr[k + 1], acc1);
        }
        float v = (acc0 + acc1) * scale[r];
        float other = __shfl_xor(v, 1);
        if (!(lane & 1))
            outb[(size_t)r * 32 + (lane >> 1)] = pk2(v, other);
    }
}

// per dst row i (one wave): halves process alternate edges, 2 bf16 dims per lane.
// out[i] = (sum_src xs[src] + xs[i]) * dinv[i] + bias   (f32 out)
__global__ __launch_bounds__(256) void k_gather2(const unsigned* __restrict__ xs, const float* __restrict__ dinv,
                                                 const int* __restrict__ row_start, const int* __restrict__ csr,
                                                 const float* __restrict__ bias, float* __restrict__ outb) {
    int i = blockIdx.x * 4 + (threadIdx.x >> 6);
    int lane = threadIdx.x & 63, half = lane >> 5, sl = lane & 31;
    int s0 = row_start[i], s1 = row_start[i + 1];
    float di = dinv[i];
    float accx = 0.f, accy = 0.f;
    if (!half) {
        unsigned pk = xs[(size_t)i * 32 + sl];
        accx = bflo(pk); accy = bfhi(pk);
    }
    int e = s0 + half;
    for (; e + 2 < s1; e += 4) {
        int ida = csr[e], idb = csr[e + 2];
        unsigned pa = xs[(size_t)ida * 32 + sl];
        unsigned pb = xs[(size_t)idb * 32 + sl];
        accx += bflo(pa) + bflo(pb);
        accy += bfhi(pa) + bfhi(pb);
    }
    for (; e < s1; e += 2) {
        unsigned pa = xs[(size_t)csr[e] * 32 + sl];
        accx += bflo(pa);
        accy += bfhi(pa);
    }
    accx += __shfl_xor(accx, 32);
    accy += __shfl_xor(accy, 32);
    if (!half) {
        float2 bb = *(const float2*)(bias + sl * 2);
        float2 o;
        o.x = fmaf(accx, di, bb.x);
        o.y = fmaf(accy, di, bb.y);
        *(float2*)(outb + (size_t)i * 64 + sl * 2) = o;
    }
}

// ---------------- MFMA attention ----------------
// 32 users/block, user padded to 8 rows -> 16-row M-tile = 2 users.
// W = CI(16x64) @ AT^T(64x48): 3 N-tiles x 2 K-steps of mfma_f32_16x16x32_bf16.
// C layout: col=l&15 (j), row=(l>>4)*4+r. lg even: s=0..3, lg odd: r0 = s4.
#define AUB 32

__global__ __launch_bounds__(256) void k_attn_mfma(
        const int* __restrict__ edge_user, const float* __restrict__ ci_table,
        const float* __restrict__ at_w, const float* __restrict__ at_b,
        const float* __restrict__ d2_w, const float* __restrict__ d2_b,
        const float* __restrict__ ue, unsigned* __restrict__ uefp) {
    __shared__ short CI[256 * 64];  // 32KB: 256 rows x 64 bf16, stride 128B, swizzled
    int t = threadIdx.x;
    int lane = t & 63, wid = t >> 6;
    int l15 = lane & 15, lg = lane >> 4;
    int half = lane >> 5, sl = lane & 31;

    // B-fragments of at_w^T: col j = nt*16+l15 (j = h*8+kk), k = ks*32+lg*8+jj
    bf16x8 bw[3][2];
#pragma unroll
    for (int nt = 0; nt < 3; ++nt) {
        int j48 = nt * 16 + l15;
        int h = j48 >> 3, kk = j48 & 7;
#pragma unroll
        for (int ks = 0; ks < 2; ++ks) {
            int kb = ks * 32 + lg * 8;
            bf16x8 f;
#pragma unroll
            for (int j = 0; j < 8; ++j) f[j] = f2bf(at_w[h * 512 + (kb + j) * 8 + kk]);
            bw[nt][ks] = f;
        }
    }
    float atbv[3], dcoef[3];
#pragma unroll
    for (int nt = 0; nt < 3; ++nt) {
        atbv[nt] = at_b[nt * 16 + l15];
        dcoef[nt] = d2_w[1 + nt * 16 + l15];
    }
    float d2w0 = d2_w[0], d2b0 = d2_b[0];

    int u0 = blockIdx.x * AUB;
    // stage ci -> LDS bf16 (2 rows per wave-iter, float2 per lane, zero pad rows)
    for (int rr = 0; rr < 32; ++rr) {
        int row = wid * 64 + rr * 2 + half;
        int uu = row >> 3, s = row & 7;
        unsigned pk = 0;
        if (s < 5) {
            int id = edge_user[U_NUM * SEQL + (u0 + uu) * SEQL + s];
            float2 v = *(const float2*)(ci_table + (size_t)id * 64 + sl * 2);
            pk = pk2(v.x, v.y);
        }
        *(unsigned*)((char*)CI + swzo(row, sl * 4, 128)) = pk;
    }
    __syncthreads();

    float evenm = (lg & 1) ? 0.f : 1.f;
    for (int mt = 0; mt < 4; ++mt) {
        int tbase = (wid * 4 + mt) * 16;
        bf16x8 a0 = *(bf16x8*)((char*)CI + swzo(tbase + l15, lg * 16, 128));
        bf16x8 a1 = *(bf16x8*)((char*)CI + swzo(tbase + l15, 64 + lg * 16, 128));
        float g0 = 0.f, g1 = 0.f, g2 = 0.f, g3 = 0.f;
#pragma unroll
        for (int nt = 0; nt < 3; ++nt) {
            f32x4 c = {0.f, 0.f, 0.f, 0.f};
            c = __builtin_amdgcn_mfma_f32_16x16x32_bf16(a0, bw[nt][0], c, 0, 0, 0);
            c = __builtin_amdgcn_mfma_f32_16x16x32_bf16(a1, bw[nt][1], c, 0, 0, 0);
            float w0 = c[0] + atbv[nt], w1 = c[1] + atbv[nt],
                  w2 = c[2] + atbv[nt], w3 = c[3] + atbv[nt];
            float e0 = __expf(1.f - __fdividef(2.f, __expf(2.f * w0) + 1.f));
            float e1 = __expf(1.f - __fdividef(2.f, __expf(2.f * w1) + 1.f));
            float e2 = __expf(1.f - __fdividef(2.f, __expf(2.f * w2) + 1.f));
            float e3 = __expf(1.f - __fdividef(2.f, __expf(2.f * w3) + 1.f));
            float partial = e0 + evenm * (e1 + e2 + e3);
            float esum = partial + __shfl_xor(partial, 16);
            float sc = __fdividef(dcoef[nt], esum);
            g0 = fmaf(e0, sc, g0);
            g1 = fmaf(e1, sc, g1);
            g2 = fmaf(e2, sc, g2);
            g3 = fmaf(e3, sc, g3);
        }
#pragma unroll
        for (int d = 1; d < 16; d <<= 1) {
            g0 += __shfl_xor(g0, d);
            g1 += __shfl_xor(g1, d);
            g2 += __shfl_xor(g2, d);
            g3 += __shfl_xor(g3, d);
        }
        // gamma scalars: user A from lanes 0/16, user B from lanes 32/48
        float gA0 = rd_lane(g0, 0), gA1 = rd_lane(g1, 0), gA2 = rd_lane(g2, 0),
              gA3 = rd_lane(g3, 0), gA4 = rd_lane(g0, 16);
        float gB0 = rd_lane(g0, 32), gB1 = rd_lane(g1, 32), gB2 = rd_lane(g2, 32),
              gB3 = rd_lane(g3, 32), gB4 = rd_lane(g0, 48);
        float gs0 = half ? gB0 : gA0;
        float gs1 = half ? gB1 : gA1;
        float gs2 = half ? gB2 : gA2;
        float gs3 = half ? gB3 : gA3;
        float gs4 = half ? gB4 : gA4;
        // uef = d2w0*ue + d2b0 + sum_s gs*ci_s ; half0 -> user A, half1 -> user B
        int urow = tbase + half * 8;
        int u = u0 + (tbase >> 3) + half;
        float2 uev = *(const float2*)(ue + (size_t)u * 64 + sl * 2);
        float rx = fmaf(d2w0, uev.x, d2b0);
        float ry = fmaf(d2w0, uev.y, d2b0);
        unsigned c0 = *(unsigned*)((char*)CI + swzo(urow + 0, sl * 4, 128));
        unsigned c1 = *(unsigned*)((char*)CI + swzo(urow + 1, sl * 4, 128));
        unsigned c2 = *(unsigned*)((char*)CI + swzo(urow + 2, sl * 4, 128));
        unsigned c3 = *(unsigned*)((char*)CI + swzo(urow + 3, sl * 4, 128));
        unsigned c4 = *(unsigned*)((char*)CI + swzo(urow + 4, sl * 4, 128));
        rx = fmaf(gs0, bflo(c0), rx); ry = fmaf(gs0, bfhi(c0), ry);
        rx = fmaf(gs1, bflo(c1), rx); ry = fmaf(gs1, bfhi(c1), ry);
        rx = fmaf(gs2, bflo(c2), rx); ry = fmaf(gs2, bfhi(c2), ry);
        rx = fmaf(gs3, bflo(c3), rx); ry = fmaf(gs3, bfhi(c3), ry);
        rx = fmaf(gs4, bflo(c4), rx); ry = fmaf(gs4, bfhi(c4), ry);
        uefp[(size_t)u * 32 + sl] = pk2(rx, ry);
    }
}

// ---------------- MFMA MLP ----------------
#define N_TILES 1563

__global__ __launch_bounds__(256, 2) void k_mlp_mfma(
        const int* __restrict__ edge_user, const float* __restrict__ ci2,
        const unsigned* __restrict__ uefg,
        const float* __restrict__ w1, const float* __restrict__ b1,
        const float* __restrict__ w2, const float* __restrict__ b2,
        const float* __restrict__ w3, const float* __restrict__ b3,
        const float* __restrict__ dw, const float* __restrict__ db,
        float* __restrict__ out) {
    __shared__ short Xa[64 * 64];     // 8KB  stride 128B, swizzled
    __shared__ short h1a[64 * 256];   // 32KB stride 512B, swizzled
    __shared__ short h2c[64 * 192];   // 24KB stride 384B, swizzled; cols 128..191 = ci2sum
    int t = threadIdx.x;
    int lane = t & 63, w = t >> 6;
    int l15 = lane & 15, lg = lane >> 4;

    bf16x8 wf1[8];
#pragma unroll
    for (int nt = 0; nt < 4; ++nt)
#pragma unroll
        for (int ks = 0; ks < 2; ++ks) {
            int col = w * 64 + nt * 16 + l15;
            int kb = ks * 32 + lg * 8;
            bf16x8 f;
#pragma unroll
            for (int j = 0; j < 8; ++j) f[j] = f2bf(w1[(kb + j) * 256 + col]);
            wf1[nt * 2 + ks] = f;
        }
    bf16x8 wf2[16];
#pragma unroll
    for (int nt = 0; nt < 2; ++nt)
#pragma unroll
        for (int ks = 0; ks < 8; ++ks) {
            int col = w * 32 + nt * 16 + l15;
            int kb = ks * 32 + lg * 8;
            bf16x8 f;
#pragma unroll
            for (int j = 0; j < 8; ++j) f[j] = f2bf(w2[(kb + j) * 128 + col]);
            wf2[nt * 8 + ks] = f;
        }
    bf16x8 wf3[12];
#pragma unroll
    for (int nt = 0; nt < 2; ++nt)
#pragma unroll
        for (int ks = 0; ks < 6; ++ks) {
            int col = w * 32 + nt * 16 + l15;
            int kb = ks * 32 + lg * 8;
            bf16x8 f;
#pragma unroll
            for (int j = 0; j < 8; ++j) {
                int k = kb + j;
                float v = 0.f;
                if (col < 120) v = (k < 128) ? w3[k * 120 + col] : dw[(k - 128) * 120 + col];
                f[j] = f2bf(v);
            }
            wf3[nt * 6 + ks] = f;
        }
    float bias1[4], bias2[2], bias3[2];
#pragma unroll
    for (int nt = 0; nt < 4; ++nt) bias1[nt] = b1[w * 64 + nt * 16 + l15];
#pragma unroll
    for (int nt = 0; nt < 2; ++nt) {
        int col = w * 32 + nt * 16 + l15;
        bias2[nt] = b2[col];
        bias3[nt] = (col < 120) ? (b3[col] + 5.f * db[col]) : 0.f;
    }

    for (int tile = blockIdx.x; tile < N_TILES; tile += gridDim.x) {
        int u0 = tile * 64;
        {   // load phase: Xa (uef bf16 copy) and ci2sum -> h2c cols 128..191
            int ur = t >> 2, d0 = (t & 3) * 16;
            int u = u0 + ur;
            bf16x8 p0 = {0, 0, 0, 0, 0, 0, 0, 0}, p1 = p0;
            if (u < U_NUM) {
                const bf16x8* up = (const bf16x8*)(uefg + (size_t)u * 32 + d0 / 2);
                p0 = up[0];
                p1 = up[1];
            }
            *(bf16x8*)((char*)Xa + swzo(ur, d0 * 2, 128)) = p0;
            *(bf16x8*)((char*)Xa + swzo(ur, d0 * 2 + 16, 128)) = p1;

            float cs[16];
#pragma unroll
            for (int q = 0; q < 16; ++q) cs[q] = 0.f;
            if (u < U_NUM) {
                const int* eb = edge_user + U_NUM * SEQL + u * SEQL;
#pragma unroll
                for (int q = 0; q < 5; ++q) {
                    const float4* cp = (const float4*)(ci2 + (size_t)eb[q] * 64 + d0);
#pragma unroll
                    for (int p = 0; p < 4; ++p) {
                        float4 v = cp[p];
                        cs[p * 4 + 0] += v.x; cs[p * 4 + 1] += v.y;
                        cs[p * 4 + 2] += v.z; cs[p * 4 + 3] += v.w;
                    }
                }
            }
            bf16x8 q0, q1;
#pragma unroll
            for (int j = 0; j < 8; ++j) { q0[j] = f2bf(cs[j]); q1[j] = f2bf(cs[8 + j]); }
            *(bf16x8*)((char*)h2c + swzo(ur, 256 + d0 * 2, 384)) = q0;
            *(bf16x8*)((char*)h2c + swzo(ur, 256 + d0 * 2 + 16, 384)) = q1;
        }
        __syncthreads();
#pragma unroll
        for (int mt = 0; mt < 4; ++mt) {  // h1 = relu(X @ W1 + b1)
            bf16x8 a0 = *(bf16x8*)((char*)Xa + swzo(mt * 16 + l15, lg * 16, 128));
            bf16x8 a1 = *(bf16x8*)((char*)Xa + swzo(mt * 16 + l15, 64 + lg * 16, 128));
#pragma unroll
            for (int nt = 0; nt < 4; ++nt) {
                f32x4 c = {0.f, 0.f, 0.f, 0.f};
                c = __builtin_amdgcn_mfma_f32_16x16x32_bf16(a0, wf1[nt * 2 + 0], c, 0, 0, 0);
                c = __builtin_amdgcn_mfma_f32_16x16x32_bf16(a1, wf1[nt * 2 + 1], c, 0, 0, 0);
                int col = w * 64 + nt * 16 + l15;
                float bb = bias1[nt];
#pragma unroll
                for (int r = 0; r < 4; ++r) {
                    int row = mt * 16 + lg * 4 + r;
                    *(short*)((char*)h1a + swzo(row, col * 2, 512)) = f2bf(fmaxf(c[r] + bb, 0.f));
                }
            }
        }
        __syncthreads();
#pragma unroll
        for (int mt = 0; mt < 4; ++mt) {  // h2 = relu(h1 @ W2 + b2)
            bf16x8 af[8];
#pragma unroll
            for (int ks = 0; ks < 8; ++ks)
                af[ks] = *(bf16x8*)((char*)h1a + swzo(mt * 16 + l15, ks * 64 + lg * 16, 512));
#pragma unroll
            for (int nt = 0; nt < 2; ++nt) {
                f32x4 c = {0.f, 0.f, 0.f, 0.f};
#pragma unroll
                for (int ks = 0; ks < 8; ++ks)
                    c = __builtin_amdgcn_mfma_f32_16x16x32_bf16(af[ks], wf2[nt * 8 + ks], c, 0, 0, 0);
                int col = w * 32 + nt * 16 + l15;
                float bb = bias2[nt];
#pragma unroll
                for (int r = 0; r < 4; ++r) {
                    int row = mt * 16 + lg * 4 + r;
                    *(short*)((char*)h2c + swzo(row, col * 2, 384)) = f2bf(fmaxf(c[r] + bb, 0.f));
                }
            }
        }
        __syncthreads();
#pragma unroll
        for (int mt = 0; mt < 4; ++mt) {  // out = [h2|ci2sum] @ [W3;dw] + biases
            bf16x8 af[6];
#pragma unroll
            for (int ks = 0; ks < 6; ++ks)
                af[ks] = *(bf16x8*)((char*)h2c + swzo(mt * 16 + l15, ks * 64 + lg * 16, 384));
#pragma unroll
            for (int nt = 0; nt < 2; ++nt) {
                f32x4 c = {0.f, 0.f, 0.f, 0.f};
#pragma unroll
                for (int ks = 0; ks < 6; ++ks)
                    c = __builtin_amdgcn_mfma_f32_16x16x32_bf16(af[ks], wf3[nt * 6 + ks], c, 0, 0, 0);
                int col = w * 32 + nt * 16 + l15;
                float bb = bias3[nt];
                if (col < 120) {
#pragma unroll
                    for (int r = 0; r < 4; ++r) {
                        int u = u0 + mt * 16 + lg * 4 + r;
                        if (u < U_NUM) out[(size_t)u * 120 + col] = c[r] + bb;
                    }
                }
            }
        }
        __syncthreads();
    }
}

extern "C" void kernel_launch(void* const* d_in, const int* in_sizes, int n_in,
                              void* d_out, int out_size, void* d_ws, size_t ws_size,
                              hipStream_t stream) {
    const int* edge_user   = (const int*)d_in[0];
    const int* u_v_edge    = (const int*)d_in[2];
    const float* user_table = (const float*)d_in[4];
    const float* ci_table   = (const float*)d_in[5];
    const float* ci_table2  = (const float*)d_in[6];
    const float* gcn1_w = (const float*)d_in[7];
    const float* gcn1_b = (const float*)d_in[8];
    const float* gcn2_w = (const float*)d_in[9];
    const float* gcn2_b = (const float*)d_in[10];
    const float* at_w = (const float*)d_in[11];
    const float* at_b = (const float*)d_in[12];
    const float* d2_w = (const float*)d_in[13];
    const float* d2_b = (const float*)d_in[14];
    const float* d1u_w = (const float*)d_in[15];
    const float* d1u_b = (const float*)d_in[16];
    const float* d2u_w = (const float*)d_in[17];
    const float* d2u_b = (const float*)d_in[18];
    const float* d3u_w = (const float*)d_in[19];
    const float* d3u_b = (const float*)d_in[20];
    const float* d1_w = (const float*)d_in[21];
    const float* d1_b = (const float*)d_in[22];
    float* out = (float*)d_out;
    char* ws = (char*)d_ws;

    int* deg       = (int*)(ws + OFF_DEG);
    int* cursor    = (int*)(ws + OFF_CURSOR);
    int* row_start = (int*)(ws + OFF_ROWSTART);
    float* dinv    = (float*)(ws + OFF_DINV);
    int* bsum      = (int*)(ws + OFF_BSUM);
    int* csr       = (int*)(ws + OFF_CSR);
    unsigned* XS   = (unsigned*)(ws + OFF_XS);
    float* B       = (float*)(ws + OFF_B);

    hipMemsetAsync(ws, 0, 800000, stream);  // deg + cursor
    k_count<<<6250, 256, 0, stream>>>(u_v_edge, deg);
    k_dinv<<<391, 256, 0, stream>>>(deg, dinv);
    k_scanA<<<98, 1024, 0, stream>>>(deg, bsum);
    k_scanB<<<1, 64, 0, stream>>>(bsum, 98);
    k_scanC<<<98, 1024, 0, stream>>>(deg, bsum, row_start);
    k_fill<<<6250, 256, 0, stream>>>(u_v_edge, row_start, cursor, csr);

    // GCN layer 1: XS = bf16((user_table @ W1) * dinv) ; B = (gather(XS)+XS)*dinv + b1
    k_gemm64b<<<1024, 256, 0, stream>>>(user_table, gcn1_w, dinv, XS, 0);
    k_gather2<<<25000, 256, 0, stream>>>(XS, dinv, row_start, csr, gcn1_b, B);
    // GCN layer 2
    k_gemm64b<<<1024, 256, 0, stream>>>(B, gcn2_w, dinv, XS, 1);
    k_gather2<<<25000, 256, 0, stream>>>(XS, dinv, row_start, csr, gcn2_b, B);

    // MFMA attention -> uef (bf16 packed, overlays XS region — XS is dead now)
    k_attn_mfma<<<3125, 256, 0, stream>>>(edge_user, ci_table, at_w, at_b, d2_w, d2_b,
                                          B, XS);
    // fused MFMA MLP + score2 (reads bf16 uef)
    k_mlp_mfma<<<512, 256, 0, stream>>>(edge_user, ci_table2, XS,
                                        d1u_w, d1u_b, d2u_w, d2u_b, d3u_w, d3u_b, d1_w, d1_b, out);
}